// Round 11
// baseline (204.028 us; speedup 1.0000x reference)
//
#include <hip/hip_runtime.h>
#include <hip/hip_fp16.h>

#define N_NODES 65536
#define N_EDGES 1048576
#define F_IN    16
#define H       64
#define N_GRAPHS 32
#define NPG     2048
#define OUT_F   12
#define KPG     (NPG * H)   // 131072 per-graph K for FC
#define CAP     4864        // padded per-bucket capacity: mean 4096, sigma 64, +12 sigma

// ================================================================ CSR build
// Edges pack into uint32: src (16b) | dst (16b) << 16.
// Bucket = dst>>8 (256 buckets of 256 nodes), FIXED padded regions of CAP edges.

// 1 tiny block: init cursors to padded bucket bases; bias-init out
__global__ __launch_bounds__(256) void init_kernel(int* __restrict__ gCursor,
                                                   const float* __restrict__ bfc,
                                                   float* __restrict__ out) {
    int t = threadIdx.x;
    gCursor[t] = t * CAP;
    for (int i = t; i < N_GRAPHS * OUT_F; i += 256) out[i] = bfc[i % OUT_F];
}

// 256 blocks x 4096 edges: LDS-staged bin by dst>>8, coalesced flush into bucket regions
__global__ __launch_bounds__(256) void binA_kernel(const int* __restrict__ src,
                                                   const int* __restrict__ dst,
                                                   int* __restrict__ gCursor,
                                                   unsigned int* __restrict__ binned) {
    __shared__ int hist[256];
    __shared__ int sc[256];
    __shared__ int bnd[256];
    __shared__ int lcur[256];
    __shared__ int blkBase[256];
    __shared__ unsigned int staged[4096];
    int t = threadIdx.x;
    hist[t] = 0; lcur[t] = 0;
    __syncthreads();
    int e0 = blockIdx.x * 4096;
    unsigned int rec[16];
#pragma unroll
    for (int i = 0; i < 16; i++) {
        int e = e0 + i * 256 + t;
        unsigned int s = (unsigned int)src[e];
        unsigned int d = (unsigned int)dst[e];
        rec[i] = s | (d << 16);
        atomicAdd(&hist[d >> 8], 1);
    }
    __syncthreads();
    int cnt = hist[t];
    if (cnt) blkBase[t] = atomicAdd(&gCursor[t], cnt);
    sc[t] = cnt;
    __syncthreads();
    for (int off = 1; off < 256; off <<= 1) {
        int v = (t >= off) ? sc[t - off] : 0;
        __syncthreads();
        sc[t] += v;
        __syncthreads();
    }
    bnd[t] = sc[t] - cnt;
    __syncthreads();
#pragma unroll
    for (int i = 0; i < 16; i++) {
        int b = rec[i] >> 24;
        int p = bnd[b] + atomicAdd(&lcur[b], 1);
        staged[p] = rec[i];
    }
    __syncthreads();
    // flush: bucket of staged[i] is its own top byte -- direct lookup, no search
    for (int i = t; i < 4096; i += 256) {
        unsigned int r = staged[i];
        int b = r >> 24;
        binned[blkBase[b] + (i - bnd[b])] = r;
    }
}

// block per bucket: counting sort -> nbr (ushort), rowinfo{start,cnt}; fused g1h write
__global__ __launch_bounds__(256) void binB_g1_kernel(const unsigned int* __restrict__ binned,
                                                      const int* __restrict__ gCursor,
                                                      const float* __restrict__ x,
                                                      int2* __restrict__ rowinfo,
                                                      unsigned short* __restrict__ nbr,
                                                      __half2* __restrict__ g1h) {
    __shared__ int hist[256];
    __shared__ int sc[256];
    __shared__ int off[256];
    __shared__ int cur[256];
    __shared__ unsigned short outS[8192];
    int b = blockIdx.x, t = threadIdx.x;
    int base = b * CAP;
    int cnt  = gCursor[b] - base;   // actual edges in this bucket after binA
    hist[t] = 0; cur[t] = 0;
    __syncthreads();
    for (int i = t; i < cnt; i += 256) {
        unsigned int r = binned[base + i];
        atomicAdd(&hist[(r >> 16) & 255], 1);
    }
    __syncthreads();
    int c = hist[t];
    sc[t] = c;
    __syncthreads();
    for (int o = 1; o < 256; o <<= 1) {
        int v = (t >= o) ? sc[t - o] : 0;
        __syncthreads();
        sc[t] += v;
        __syncthreads();
    }
    off[t] = sc[t] - c;
    int nd = (b << 8) + t;
    float dv = rsqrtf((float)(c + 1));
    rowinfo[nd] = make_int2(base + sc[t] - c, c);
    {
        const float4* xr = (const float4*)(x + (size_t)nd * F_IN);
        float4 x0 = xr[0], x1 = xr[1], x2 = xr[2], x3 = xr[3];
        __half2* gr = g1h + nd * 8;
        gr[0] = __floats2half2_rn(x0.x * dv, x0.y * dv);
        gr[1] = __floats2half2_rn(x0.z * dv, x0.w * dv);
        gr[2] = __floats2half2_rn(x1.x * dv, x1.y * dv);
        gr[3] = __floats2half2_rn(x1.z * dv, x1.w * dv);
        gr[4] = __floats2half2_rn(x2.x * dv, x2.y * dv);
        gr[5] = __floats2half2_rn(x2.z * dv, x2.w * dv);
        gr[6] = __floats2half2_rn(x3.x * dv, x3.y * dv);
        gr[7] = __floats2half2_rn(x3.z * dv, x3.w * dv);
    }
    __syncthreads();
    for (int i = t; i < cnt; i += 256) {
        unsigned int r = binned[base + i];
        int n = (r >> 16) & 255;
        int p = off[n] + atomicAdd(&cur[n], 1);
        outS[p] = (unsigned short)(r & 0xFFFF);
    }
    __syncthreads();
    for (int i = t; i < cnt; i += 256) nbr[base + i] = outS[i];
}

// ---------------------------------------------------------------- helpers
__device__ __forceinline__ void add8(float* acc, float4 q) {
    union { float4 f; __half2 h[4]; } u; u.f = q;
#pragma unroll
    for (int c = 0; c < 4; c++) {
        float2 p = __half22float2(u.h[c]);
        acc[2 * c]     += p.x;
        acc[2 * c + 1] += p.y;
    }
}
__device__ __forceinline__ void add4(float* acc, float2 q) {
    union { float2 f; __half2 h[2]; } u; u.f = q;
    float2 p0 = __half22float2(u.h[0]);
    float2 p1 = __half22float2(u.h[1]);
    acc[0] += p0.x; acc[1] += p0.y; acc[2] += p1.x; acc[3] += p1.y;
}
// tanh via hardware exp: ~1e-7 abs error, saturates correctly at +-inf
__device__ __forceinline__ float tanh_fast(float x) {
    float e = __expf(2.f * x);
    return 1.f - 2.f / (e + 1.f);
}

// ================================================================ layer 1: fused agg + gemm (LDS handoff)
// 64 nodes/block. Gather phase (identical per-node structure to the proven
// agg1): wave w handles nodes v0+it*4+w, 16 its; result rows land in LDS As
// instead of global a1. One barrier, then the proven LDS-blocked K=16 GEMM.
__global__ __launch_bounds__(256) void agg1_gemm1_kernel(const __half2* __restrict__ g1h,
                                                         const int2* __restrict__ rowinfo,
                                                         const unsigned short* __restrict__ nbr,
                                                         const float* __restrict__ W1,
                                                         const float* __restrict__ b1,
                                                         __half* __restrict__ g2h) {
    const float2* g1v = (const float2*)g1h;   // row = 4 float2
    __shared__ float Ws[F_IN * H];   // 4 KB
    __shared__ float As[64 * F_IN];  // 4 KB, [node][k]
    __shared__ float bs[H];
    __shared__ float dvs[64];
    int t = threadIdx.x;
    for (int i = t; i < F_IN * H; i += 256) Ws[i] = W1[i];
    if (t < H) bs[t] = b1[t];
    int lane = t & 63;
    int w    = t >> 6;
    int f4   = lane & 3;
    int sub  = lane >> 2;          // 16 edge-slots per batch
    int v0   = blockIdx.x * 64;
    int v    = v0 + w;
    int2 ri  = rowinfo[v];
    int nb   = (int)nbr[ri.x + lane];
#pragma unroll 1
    for (int it = 0; it < 16; ++it) {
        int vc = v;
        int r0 = ri.x, er = ri.y;
        int nbc = nb;
        float2 sq = g1v[(vc << 2) + f4];      // self row, early
        int s0 = sub, s1 = 16 + sub;
        int u0 = __shfl(nbc, s0 < er ? s0 : 0, 64);
        int u1 = __shfl(nbc, s1 < er ? s1 : 0, 64);
        float2 q0 = make_float2(0.f, 0.f), q1 = make_float2(0.f, 0.f);
        if (s0 < er) q0 = g1v[(u0 << 2) + f4];
        if (s1 < er) q1 = g1v[(u1 << 2) + f4];
        if (it < 15) ri = rowinfo[vc + 4];    // prefetch next rowinfo
        float acc[4] = {0.f, 0.f, 0.f, 0.f};
        add4(acc, q0);
        add4(acc, q1);
        int j = 32;
        for (; j + 32 <= er; j += 32) {
            int a0 = __shfl(nbc, j + sub, 64);
            int a1i = __shfl(nbc, j + 16 + sub, 64);
            float2 t0 = g1v[(a0 << 2) + f4];
            float2 t1 = g1v[(a1i << 2) + f4];
            add4(acc, t0);
            add4(acc, t1);
        }
        for (; j < er && j < 64; j += 16) {
            int idx = j + sub;
            int u = __shfl(nbc, idx < er ? idx : 0, 64);
            if (idx < er) { float2 q = g1v[(u << 2) + f4]; add4(acc, q); }
        }
        for (int base = 64; base < er; base += 64) {   // essentially never (deg>64)
            int nbx = (int)nbr[r0 + base + lane];
            for (int jj = 0; jj < 64 && base + jj < er; jj += 16) {
                int idx = jj + sub;
                int u = __shfl(nbx, (base + idx) < er ? idx : 0, 64);
                if (base + idx < er) { float2 q = g1v[(u << 2) + f4]; add4(acc, q); }
            }
        }
        if (it < 15) nb = (int)nbr[ri.x + lane];  // prefetch next nbr chunk
#pragma unroll
        for (int i = 0; i < 4; i++) {
            acc[i] += __shfl_xor(acc[i], 4, 64);
            acc[i] += __shfl_xor(acc[i], 8, 64);
            acc[i] += __shfl_xor(acc[i], 16, 64);
            acc[i] += __shfl_xor(acc[i], 32, 64);
        }
        add4(acc, sq);
        float dv = rsqrtf((float)(er + 1));
        int nloc = (it << 2) + w;
        if (sub == 0) {
            *(float4*)&As[nloc * F_IN + (f4 << 2)] =
                make_float4(dv * acc[0], dv * acc[1], dv * acc[2], dv * acc[3]);
            if (f4 == 0) dvs[nloc] = dv;
        }
        v += 4;
    }
    __syncthreads();
    // GEMM phase: wave w handles nodes w*16..w*16+15 (LDS remap via barrier)
    float acg[16];
#pragma unroll
    for (int j = 0; j < 16; j++) acg[j] = bs[lane];
    const float* asBase = As + ((w << 4) * F_IN);
#pragma unroll
    for (int kc = 0; kc < F_IN / 4; ++kc) {
        int k0 = kc << 2;
        float w0 = Ws[(k0 + 0) * H + lane];
        float w1 = Ws[(k0 + 1) * H + lane];
        float w2 = Ws[(k0 + 2) * H + lane];
        float w3 = Ws[(k0 + 3) * H + lane];
#pragma unroll
        for (int j = 0; j < 16; ++j) {
            float4 aq = *(const float4*)(asBase + j * F_IN + k0);   // wave-uniform -> broadcast
            acg[j] += aq.x * w0 + aq.y * w1 + aq.z * w2 + aq.w * w3;
        }
    }
    int vw = v0 + (w << 4);
#pragma unroll
    for (int j = 0; j < 16; ++j) {
        float dv = dvs[(w << 4) + j];
        g2h[((size_t)(vw + j) << 6) + lane] = __float2half(dv * tanh_fast(acg[j]));
    }
}

// ================================================================ layer 2: fused agg + gemm + FC (LDS handoff)
// 64 nodes/block. Gather phase identical to the proven agg2; a2 rows land in
// LDS As (already dinv-scaled). One barrier, then the proven gemm2_fc body.
__global__ __launch_bounds__(256) void agg2_gemm2_fc_kernel(const __half2* __restrict__ g2h,
                                                            const int2* __restrict__ rowinfo,
                                                            const unsigned short* __restrict__ nbr,
                                                            const float* __restrict__ W2,
                                                            const float* __restrict__ b2,
                                                            const float* __restrict__ Wfc,
                                                            float* __restrict__ out) {
    const float4* g2v = (const float4*)g2h;   // row = 8 float4
    __shared__ float Ws[H * H];     // 16 KB, [k][o]
    __shared__ float As[64 * H];    // 16 KB, [node][k]
    __shared__ float bs[H];
    __shared__ float red[4][OUT_F];
    int t = threadIdx.x;
    for (int i = t; i < H * H; i += 256) Ws[i] = W2[i];   // hides under gathers
    if (t < H) bs[t] = b2[t];
    int lane = t & 63;
    int w    = t >> 6;
    int f8   = lane & 7;
    int sub  = lane >> 3;          // 8 edge-slots per batch
    int v0   = blockIdx.x * 64;
    int v    = v0 + w;
    int2 ri  = rowinfo[v];
    int nb   = (int)nbr[ri.x + lane];
#pragma unroll 1
    for (int it = 0; it < 16; ++it) {
        int vc = v;
        int r0 = ri.x, er = ri.y;
        int nbc = nb;
        float4 sq = g2v[(vc << 3) + f8];      // self row, early
        int s0 = sub, s1 = 8 + sub, s2 = 16 + sub, s3 = 24 + sub;
        int u0 = __shfl(nbc, s0 < er ? s0 : 0, 64);
        int u1 = __shfl(nbc, s1 < er ? s1 : 0, 64);
        int u2 = __shfl(nbc, s2 < er ? s2 : 0, 64);
        int u3 = __shfl(nbc, s3 < er ? s3 : 0, 64);
        float4 q0 = make_float4(0.f, 0.f, 0.f, 0.f);
        float4 q1 = q0, q2 = q0, q3 = q0;
        if (s0 < er) q0 = g2v[(u0 << 3) + f8];
        if (s1 < er) q1 = g2v[(u1 << 3) + f8];
        if (s2 < er) q2 = g2v[(u2 << 3) + f8];
        if (s3 < er) q3 = g2v[(u3 << 3) + f8];
        if (it < 15) ri = rowinfo[vc + 4];    // prefetch next rowinfo
        float acc[8] = {0.f, 0.f, 0.f, 0.f, 0.f, 0.f, 0.f, 0.f};
        add8(acc, q0);
        add8(acc, q1);
        add8(acc, q2);
        add8(acc, q3);
        int j = 32;
        for (; j + 16 <= er && j < 64; j += 16) {
            int a0 = __shfl(nbc, j + sub, 64);
            int a1i = __shfl(nbc, j + 8 + sub, 64);
            float4 t0 = g2v[(a0 << 3) + f8];
            float4 t1 = g2v[(a1i << 3) + f8];
            add8(acc, t0);
            add8(acc, t1);
        }
        for (; j < er && j < 64; j += 8) {
            int idx = j + sub;
            int u = __shfl(nbc, idx < er ? idx : 0, 64);
            if (idx < er) { float4 q = g2v[(u << 3) + f8]; add8(acc, q); }
        }
        for (int base = 64; base < er; base += 64) {   // essentially never (deg>64)
            int nbx = (int)nbr[r0 + base + lane];
            for (int jj = 0; jj < 64 && base + jj < er; jj += 8) {
                int idx = jj + sub;
                int u = __shfl(nbx, (base + idx) < er ? idx : 0, 64);
                if (base + idx < er) { float4 q = g2v[(u << 3) + f8]; add8(acc, q); }
            }
        }
        if (it < 15) nb = (int)nbr[ri.x + lane];  // prefetch next nbr chunk
#pragma unroll
        for (int i = 0; i < 8; i++) {
            acc[i] += __shfl_xor(acc[i], 8, 64);
            acc[i] += __shfl_xor(acc[i], 16, 64);
            acc[i] += __shfl_xor(acc[i], 32, 64);
        }
        add8(acc, sq);
        float dv = rsqrtf((float)(er + 1));
        int nloc = (it << 2) + w;
        if (sub == 0) {
            float* dp = &As[nloc * H + (f8 << 3)];
            *(float4*)(dp)     = make_float4(dv * acc[0], dv * acc[1], dv * acc[2], dv * acc[3]);
            *(float4*)(dp + 4) = make_float4(dv * acc[4], dv * acc[5], dv * acc[6], dv * acc[7]);
        }
        v += 4;
    }
    __syncthreads();
    // GEMM + FC phase (proven gemm2_fc body; As from LDS handoff)
    int vw = v0 + (w << 4);
    int g  = blockIdx.x >> 5;               // 32 blocks per graph
    float acg[16];
#pragma unroll
    for (int j = 0; j < 16; j++) acg[j] = bs[lane];
    const float* asBase = As + ((w << 4) * H);
#pragma unroll 2
    for (int kc = 0; kc < H / 4; ++kc) {
        int k0 = kc << 2;
        float w0 = Ws[(k0 + 0) * H + lane];
        float w1 = Ws[(k0 + 1) * H + lane];
        float w2 = Ws[(k0 + 2) * H + lane];
        float w3 = Ws[(k0 + 3) * H + lane];
#pragma unroll
        for (int j = 0; j < 16; ++j) {
            float4 aq = *(const float4*)(asBase + j * H + k0);   // wave-uniform -> broadcast
            acg[j] += aq.x * w0 + aq.y * w1 + aq.z * w2 + aq.w * w3;
        }
    }
    float pa[OUT_F];
#pragma unroll
    for (int j = 0; j < OUT_F; j++) pa[j] = 0.f;
#pragma unroll
    for (int j = 0; j < 16; ++j) {
        float hv = tanh_fast(acg[j]);
        int vl = (vw + j) & (NPG - 1);
        const float4* wr = (const float4*)(Wfc + (size_t)(vl * H + lane) * OUT_F);
        float4 q0 = wr[0], q1 = wr[1], q2 = wr[2];
        pa[0]  += hv * q0.x;  pa[1]  += hv * q0.y;
        pa[2]  += hv * q0.z;  pa[3]  += hv * q0.w;
        pa[4]  += hv * q1.x;  pa[5]  += hv * q1.y;
        pa[6]  += hv * q1.z;  pa[7]  += hv * q1.w;
        pa[8]  += hv * q2.x;  pa[9]  += hv * q2.y;
        pa[10] += hv * q2.z;  pa[11] += hv * q2.w;
    }
#pragma unroll
    for (int j = 0; j < OUT_F; j++) {
        float vv = pa[j];
        vv += __shfl_xor(vv, 1, 64);  vv += __shfl_xor(vv, 2, 64);
        vv += __shfl_xor(vv, 4, 64);  vv += __shfl_xor(vv, 8, 64);
        vv += __shfl_xor(vv, 16, 64); vv += __shfl_xor(vv, 32, 64);
        pa[j] = vv;
    }
    if (lane == 0) {
#pragma unroll
        for (int j = 0; j < OUT_F; j++) red[w][j] = pa[j];
    }
    __syncthreads();
    if (t < OUT_F)
        atomicAdd(&out[g * OUT_F + t], red[0][t] + red[1][t] + red[2][t] + red[3][t]);
}

// ================================================================ launcher
extern "C" void kernel_launch(void* const* d_in, const int* in_sizes, int n_in,
                              void* d_out, int out_size, void* d_ws, size_t ws_size,
                              hipStream_t stream) {
    const float* x    = (const float*)d_in[0];
    const int*   edge = (const int*)d_in[1];
    const int*   src  = edge;
    const int*   dst  = edge + N_EDGES;
    const float* W1  = (const float*)d_in[3];
    const float* b1  = (const float*)d_in[4];
    const float* W2  = (const float*)d_in[5];
    const float* b2  = (const float*)d_in[6];
    const float* Wfc = (const float*)d_in[7];
    const float* bfc = (const float*)d_in[8];
    float* out = (float*)d_out;

    char* p = (char*)d_ws;
    auto alloc = [&](size_t n) { char* r = p; p += (n + 255) & ~(size_t)255; return r; };
    int*   gCursor    = (int*)alloc(256 * 4);
    int2*  rowinfo    = (int2*)alloc((size_t)N_NODES * 8);
    unsigned short* nbr = (unsigned short*)alloc((size_t)256 * CAP * 2 + 256); // pad: prefetch reads up to +63
    __half* g1h       = (__half*)alloc((size_t)N_NODES * F_IN * 2);
    __half* g2h       = (__half*)alloc((size_t)N_NODES * H * 2);
    unsigned int* binned = (unsigned int*)alloc((size_t)256 * CAP * 4);

    init_kernel<<<1, 256, 0, stream>>>(gCursor, bfc, out);
    binA_kernel<<<256, 256, 0, stream>>>(src, dst, gCursor, binned);
    binB_g1_kernel<<<256, 256, 0, stream>>>(binned, gCursor, x, rowinfo, nbr,
                                            (__half2*)g1h);
    agg1_gemm1_kernel<<<N_NODES / 64, 256, 0, stream>>>((const __half2*)g1h, rowinfo, nbr,
                                                        W1, b1, g2h);
    agg2_gemm2_fc_kernel<<<N_NODES / 64, 256, 0, stream>>>((const __half2*)g2h, rowinfo, nbr,
                                                           W2, b2, Wfc, out);
}

// Round 12
// 184.115 us; speedup vs baseline: 1.1082x; 1.1082x over previous
//
#include <hip/hip_runtime.h>
#include <hip/hip_fp16.h>

#define N_NODES 65536
#define N_EDGES 1048576
#define F_IN    16
#define H       64
#define N_GRAPHS 32
#define NPG     2048
#define OUT_F   12
#define KPG     (NPG * H)   // 131072 per-graph K for FC
#define CAP     4864        // padded per-bucket capacity: mean 4096, sigma 64, +12 sigma
#define NPB     16          // nodes per block in agg kernels

// ================================================================ CSR build
// Edges pack into uint32: src (16b) | dst (16b) << 16.
// Bucket = dst>>8 (256 buckets of 256 nodes), FIXED padded regions of CAP edges.

// 1 tiny block: init cursors to padded bucket bases; bias-init out
__global__ __launch_bounds__(256) void init_kernel(int* __restrict__ gCursor,
                                                   const float* __restrict__ bfc,
                                                   float* __restrict__ out) {
    int t = threadIdx.x;
    gCursor[t] = t * CAP;
    for (int i = t; i < N_GRAPHS * OUT_F; i += 256) out[i] = bfc[i % OUT_F];
}

// 256 blocks x 4096 edges: LDS-staged bin by dst>>8, coalesced flush into bucket regions
__global__ __launch_bounds__(256) void binA_kernel(const int* __restrict__ src,
                                                   const int* __restrict__ dst,
                                                   int* __restrict__ gCursor,
                                                   unsigned int* __restrict__ binned) {
    __shared__ int hist[256];
    __shared__ int sc[256];
    __shared__ int bnd[256];
    __shared__ int lcur[256];
    __shared__ int blkBase[256];
    __shared__ unsigned int staged[4096];
    int t = threadIdx.x;
    hist[t] = 0; lcur[t] = 0;
    __syncthreads();
    int e0 = blockIdx.x * 4096;
    unsigned int rec[16];
#pragma unroll
    for (int i = 0; i < 16; i++) {
        int e = e0 + i * 256 + t;
        unsigned int s = (unsigned int)src[e];
        unsigned int d = (unsigned int)dst[e];
        rec[i] = s | (d << 16);
        atomicAdd(&hist[d >> 8], 1);
    }
    __syncthreads();
    int cnt = hist[t];
    if (cnt) blkBase[t] = atomicAdd(&gCursor[t], cnt);
    sc[t] = cnt;
    __syncthreads();
    for (int off = 1; off < 256; off <<= 1) {
        int v = (t >= off) ? sc[t - off] : 0;
        __syncthreads();
        sc[t] += v;
        __syncthreads();
    }
    bnd[t] = sc[t] - cnt;
    __syncthreads();
#pragma unroll
    for (int i = 0; i < 16; i++) {
        int b = rec[i] >> 24;
        int p = bnd[b] + atomicAdd(&lcur[b], 1);
        staged[p] = rec[i];
    }
    __syncthreads();
    // flush: bucket of staged[i] is its own top byte -- direct lookup, no search
    for (int i = t; i < 4096; i += 256) {
        unsigned int r = staged[i];
        int b = r >> 24;
        binned[blkBase[b] + (i - bnd[b])] = r;
    }
}

// block per bucket: counting sort -> nbr (ushort), rowinfo{start,cnt}; fused g1h write
__global__ __launch_bounds__(256) void binB_g1_kernel(const unsigned int* __restrict__ binned,
                                                      const int* __restrict__ gCursor,
                                                      const float* __restrict__ x,
                                                      int2* __restrict__ rowinfo,
                                                      unsigned short* __restrict__ nbr,
                                                      __half2* __restrict__ g1h) {
    __shared__ int hist[256];
    __shared__ int sc[256];
    __shared__ int off[256];
    __shared__ int cur[256];
    __shared__ unsigned short outS[8192];
    int b = blockIdx.x, t = threadIdx.x;
    int base = b * CAP;
    int cnt  = gCursor[b] - base;   // actual edges in this bucket after binA
    hist[t] = 0; cur[t] = 0;
    __syncthreads();
    for (int i = t; i < cnt; i += 256) {
        unsigned int r = binned[base + i];
        atomicAdd(&hist[(r >> 16) & 255], 1);
    }
    __syncthreads();
    int c = hist[t];
    sc[t] = c;
    __syncthreads();
    for (int o = 1; o < 256; o <<= 1) {
        int v = (t >= o) ? sc[t - o] : 0;
        __syncthreads();
        sc[t] += v;
        __syncthreads();
    }
    off[t] = sc[t] - c;
    int nd = (b << 8) + t;
    float dv = rsqrtf((float)(c + 1));
    rowinfo[nd] = make_int2(base + sc[t] - c, c);
    {
        const float4* xr = (const float4*)(x + (size_t)nd * F_IN);
        float4 x0 = xr[0], x1 = xr[1], x2 = xr[2], x3 = xr[3];
        __half2* gr = g1h + nd * 8;
        gr[0] = __floats2half2_rn(x0.x * dv, x0.y * dv);
        gr[1] = __floats2half2_rn(x0.z * dv, x0.w * dv);
        gr[2] = __floats2half2_rn(x1.x * dv, x1.y * dv);
        gr[3] = __floats2half2_rn(x1.z * dv, x1.w * dv);
        gr[4] = __floats2half2_rn(x2.x * dv, x2.y * dv);
        gr[5] = __floats2half2_rn(x2.z * dv, x2.w * dv);
        gr[6] = __floats2half2_rn(x3.x * dv, x3.y * dv);
        gr[7] = __floats2half2_rn(x3.z * dv, x3.w * dv);
    }
    __syncthreads();
    for (int i = t; i < cnt; i += 256) {
        unsigned int r = binned[base + i];
        int n = (r >> 16) & 255;
        int p = off[n] + atomicAdd(&cur[n], 1);
        outS[p] = (unsigned short)(r & 0xFFFF);
    }
    __syncthreads();
    for (int i = t; i < cnt; i += 256) nbr[base + i] = outS[i];
}

// ---------------------------------------------------------------- helpers
__device__ __forceinline__ void add8(float* acc, float4 q) {
    union { float4 f; __half2 h[4]; } u; u.f = q;
#pragma unroll
    for (int c = 0; c < 4; c++) {
        float2 p = __half22float2(u.h[c]);
        acc[2 * c]     += p.x;
        acc[2 * c + 1] += p.y;
    }
}
__device__ __forceinline__ void add4(float* acc, float2 q) {
    union { float2 f; __half2 h[2]; } u; u.f = q;
    float2 p0 = __half22float2(u.h[0]);
    float2 p1 = __half22float2(u.h[1]);
    acc[0] += p0.x; acc[1] += p0.y; acc[2] += p1.x; acc[3] += p1.y;
}
// tanh via hardware exp: ~1e-7 abs error, saturates correctly at +-inf
__device__ __forceinline__ float tanh_fast(float x) {
    float e = __expf(2.f * x);
    return 1.f - 2.f / (e + 1.f);
}

// ================================================================ layer 1 (fused agg + gemm)
// Wave-per-node, upfront-batched exec-masked gathers; 16-feature GEMM in-wave
// (only 16 shfls/node -- cheap enough to keep fused, saves a launch + a1 trip).
__global__ __launch_bounds__(256) void agg1_gemm1_kernel(const __half2* __restrict__ g1h,
                                                         const int2* __restrict__ rowinfo,
                                                         const unsigned short* __restrict__ nbr,
                                                         const float* __restrict__ W1,
                                                         const float* __restrict__ b1,
                                                         __half* __restrict__ g2h) {
    const float2* g1v = (const float2*)g1h;   // row = 4 float2
    __shared__ float Ws[F_IN * H];
    __shared__ float bs[H];
    int t = threadIdx.x;
    for (int i = t; i < F_IN * H; i += 256) Ws[i] = W1[i];
    if (t < H) bs[t] = b1[t];
    __syncthreads();
    int lane = t & 63;
    int w    = t >> 6;
    int f4   = lane & 3;
    int sub  = lane >> 2;          // 16 edge-slots per batch
    int v    = blockIdx.x * NPB + w;
    int2 ri  = rowinfo[v];
    int nb   = (int)nbr[ri.x + lane];
#pragma unroll 1
    for (int it = 0; it < NPB / 4; ++it) {
        int vc = v;
        int r0 = ri.x, er = ri.y;
        int nbc = nb;
        float2 sq = g1v[(vc << 2) + f4];      // self row, early
        // upfront: edges 0..31 via 2 exec-masked loads, issued before any add
        int s0 = sub, s1 = 16 + sub;
        int u0 = __shfl(nbc, s0 < er ? s0 : 0, 64);
        int u1 = __shfl(nbc, s1 < er ? s1 : 0, 64);
        float2 q0 = make_float2(0.f, 0.f), q1 = make_float2(0.f, 0.f);
        if (s0 < er) q0 = g1v[(u0 << 2) + f4];
        if (s1 < er) q1 = g1v[(u1 << 2) + f4];
        if (it < NPB / 4 - 1) ri = rowinfo[vc + 4];   // prefetch next rowinfo
        float acc[4] = {0.f, 0.f, 0.f, 0.f};
        add4(acc, q0);
        add4(acc, q1);
        // tail: er > 32 (rare)
        int j = 32;
        for (; j + 32 <= er; j += 32) {
            int a0 = __shfl(nbc, j + sub, 64);
            int a1i = __shfl(nbc, j + 16 + sub, 64);
            float2 t0 = g1v[(a0 << 2) + f4];
            float2 t1 = g1v[(a1i << 2) + f4];
            add4(acc, t0);
            add4(acc, t1);
        }
        for (; j < er && j < 64; j += 16) {
            int idx = j + sub;
            int u = __shfl(nbc, idx < er ? idx : 0, 64);
            if (idx < er) {
                float2 q = g1v[(u << 2) + f4];
                add4(acc, q);
            }
        }
        for (int base = 64; base < er; base += 64) {   // essentially never (deg>64)
            int nbx = (int)nbr[r0 + base + lane];
            for (int jj = 0; jj < 64 && base + jj < er; jj += 16) {
                int idx = jj + sub;
                int u = __shfl(nbx, (base + idx) < er ? idx : 0, 64);
                if (base + idx < er) {
                    float2 q = g1v[(u << 2) + f4];
                    add4(acc, q);
                }
            }
        }
        if (it < NPB / 4 - 1) nb = (int)nbr[ri.x + lane];  // prefetch next nbr chunk
#pragma unroll
        for (int i = 0; i < 4; i++) {
            acc[i] += __shfl_xor(acc[i], 4, 64);
            acc[i] += __shfl_xor(acc[i], 8, 64);
            acc[i] += __shfl_xor(acc[i], 16, 64);
            acc[i] += __shfl_xor(acc[i], 32, 64);
        }
        add4(acc, sq);
        float dv = rsqrtf((float)(er + 1));
#pragma unroll
        for (int i = 0; i < 4; i++) acc[i] *= dv;
        // in-wave GEMM: feature k lives at lane (k>>2), component (k&3)
        float s = bs[lane];
#pragma unroll
        for (int k = 0; k < F_IN; ++k) {
            float bk = __shfl(acc[k & 3], k >> 2, 64);
            s += bk * Ws[k * H + lane];
        }
        g2h[(vc << 6) + lane] = __float2half(dv * tanh_fast(s));
        v += 4;
    }
}

// ================================================================ layer 2 aggregation (PURE gather)
// Wave-per-node. 4 exec-masked float4 loads covering edges 0..31 issue before
// any unpack; inactive sub-groups cost zero memory transactions. No LDS, no
// in-wave GEMM (the 64-deep serial shfl-FMA chain lives in gemm2_fc).
__global__ __launch_bounds__(256) void agg2_kernel(const __half2* __restrict__ g2h,
                                                   const int2* __restrict__ rowinfo,
                                                   const unsigned short* __restrict__ nbr,
                                                   float* __restrict__ a2) {
    const float4* g2v = (const float4*)g2h;   // row = 8 float4
    int t    = threadIdx.x;
    int lane = t & 63;
    int w    = t >> 6;
    int f8   = lane & 7;
    int sub  = lane >> 3;          // 8 edge-slots per batch
    int v    = blockIdx.x * NPB + w;
    int2 ri  = rowinfo[v];
    int nb   = (int)nbr[ri.x + lane];
#pragma unroll 1
    for (int it = 0; it < NPB / 4; ++it) {
        int vc = v;
        int r0 = ri.x, er = ri.y;
        int nbc = nb;
        float4 sq = g2v[(vc << 3) + f8];      // self row, early
        // upfront: edges 0..31 via 4 exec-masked loads
        int s0 = sub, s1 = 8 + sub, s2 = 16 + sub, s3 = 24 + sub;
        int u0 = __shfl(nbc, s0 < er ? s0 : 0, 64);
        int u1 = __shfl(nbc, s1 < er ? s1 : 0, 64);
        int u2 = __shfl(nbc, s2 < er ? s2 : 0, 64);
        int u3 = __shfl(nbc, s3 < er ? s3 : 0, 64);
        float4 q0 = make_float4(0.f, 0.f, 0.f, 0.f);
        float4 q1 = q0, q2 = q0, q3 = q0;
        if (s0 < er) q0 = g2v[(u0 << 3) + f8];
        if (s1 < er) q1 = g2v[(u1 << 3) + f8];
        if (s2 < er) q2 = g2v[(u2 << 3) + f8];
        if (s3 < er) q3 = g2v[(u3 << 3) + f8];
        if (it < NPB / 4 - 1) ri = rowinfo[vc + 4];   // prefetch next rowinfo
        float acc[8] = {0.f, 0.f, 0.f, 0.f, 0.f, 0.f, 0.f, 0.f};
        add8(acc, q0);
        add8(acc, q1);
        add8(acc, q2);
        add8(acc, q3);
        // tail: er > 32 (rare)
        int j = 32;
        for (; j + 16 <= er && j < 64; j += 16) {
            int a0 = __shfl(nbc, j + sub, 64);
            int a1i = __shfl(nbc, j + 8 + sub, 64);
            float4 t0 = g2v[(a0 << 3) + f8];
            float4 t1 = g2v[(a1i << 3) + f8];
            add8(acc, t0);
            add8(acc, t1);
        }
        for (; j < er && j < 64; j += 8) {
            int idx = j + sub;
            int u = __shfl(nbc, idx < er ? idx : 0, 64);
            if (idx < er) {
                float4 q = g2v[(u << 3) + f8];
                add8(acc, q);
            }
        }
        for (int base = 64; base < er; base += 64) {   // essentially never (deg>64)
            int nbx = (int)nbr[r0 + base + lane];
            for (int jj = 0; jj < 64 && base + jj < er; jj += 8) {
                int idx = jj + sub;
                int u = __shfl(nbx, (base + idx) < er ? idx : 0, 64);
                if (base + idx < er) {
                    float4 q = g2v[(u << 3) + f8];
                    add8(acc, q);
                }
            }
        }
        if (it < NPB / 4 - 1) nb = (int)nbr[ri.x + lane];  // prefetch next nbr chunk
#pragma unroll
        for (int i = 0; i < 8; i++) {
            acc[i] += __shfl_xor(acc[i], 8, 64);
            acc[i] += __shfl_xor(acc[i], 16, 64);
            acc[i] += __shfl_xor(acc[i], 32, 64);
        }
        add8(acc, sq);
        float dv = rsqrtf((float)(er + 1));
#pragma unroll
        for (int i = 0; i < 8; i++) acc[i] *= dv;
        if (sub == 0) {
            float4* dp = (float4*)(a2 + ((size_t)vc << 6) + (f8 << 3));
            dp[0] = make_float4(acc[0], acc[1], acc[2], acc[3]);
            dp[1] = make_float4(acc[4], acc[5], acc[6], acc[7]);
        }
        v += 4;
    }
}

// ================================================================ gemm2 + fused FC head
// 64 nodes/block, 16 nodes/WAVE (lane = output o, acc[16] statically indexed).
// Per k-chunk of 4: 4 conflict-free b32 Ws column reads (reused across 16 nodes)
// + 16 same-address b128 broadcast a-reads (reused across 64 outputs).
// Wfc slices read per node (L2/L3-resident, verified by FETCH_SIZE ~11 MB).
__global__ __launch_bounds__(256) void gemm2_fc_kernel(const float* __restrict__ a2,
                                                       const float* __restrict__ W2,
                                                       const float* __restrict__ b2,
                                                       const float* __restrict__ Wfc,
                                                       float* __restrict__ out) {
    __shared__ float Ws[H * H];     // 16 KB, [k][o]
    __shared__ float As[64 * H];    // 16 KB, [node][k]
    __shared__ float bs[H];
    __shared__ float red[4][OUT_F];
    int t = threadIdx.x;
    for (int i = t; i < H * H; i += 256) Ws[i] = W2[i];
    if (t < H) bs[t] = b2[t];
    {   // stage 64 a2 rows: 16 KB, 4 float4 per thread, coalesced
        const float4* ap = (const float4*)(a2 + ((size_t)blockIdx.x << 12));
        float4* asp = (float4*)As;
#pragma unroll
        for (int i = 0; i < 4; i++) asp[i * 256 + t] = ap[i * 256 + t];
    }
    __syncthreads();
    int lane = t & 63, w = t >> 6;
    int v0 = blockIdx.x * 64 + (w << 4);    // first node of this wave
    int g  = blockIdx.x >> 5;               // 32 blocks per graph
    float acc[16];
#pragma unroll
    for (int j = 0; j < 16; j++) acc[j] = bs[lane];
    const float* asBase = As + ((w << 4) * H);
#pragma unroll 2
    for (int kc = 0; kc < H / 4; ++kc) {
        int k0 = kc << 2;
        float w0 = Ws[(k0 + 0) * H + lane];
        float w1 = Ws[(k0 + 1) * H + lane];
        float w2 = Ws[(k0 + 2) * H + lane];
        float w3 = Ws[(k0 + 3) * H + lane];
#pragma unroll
        for (int j = 0; j < 16; ++j) {
            float4 aq = *(const float4*)(asBase + j * H + k0);   // wave-uniform -> broadcast
            acc[j] += aq.x * w0 + aq.y * w1 + aq.z * w2 + aq.w * w3;
        }
    }
    // FC head: fold h = tanh(acc) into graph output via Wfc slice
    float pa[OUT_F];
#pragma unroll
    for (int j = 0; j < OUT_F; j++) pa[j] = 0.f;
#pragma unroll
    for (int j = 0; j < 16; ++j) {
        float hv = tanh_fast(acc[j]);
        int vl = (v0 + j) & (NPG - 1);
        const float4* wr = (const float4*)(Wfc + (size_t)(vl * H + lane) * OUT_F);
        float4 q0 = wr[0], q1 = wr[1], q2 = wr[2];
        pa[0]  += hv * q0.x;  pa[1]  += hv * q0.y;
        pa[2]  += hv * q0.z;  pa[3]  += hv * q0.w;
        pa[4]  += hv * q1.x;  pa[5]  += hv * q1.y;
        pa[6]  += hv * q1.z;  pa[7]  += hv * q1.w;
        pa[8]  += hv * q2.x;  pa[9]  += hv * q2.y;
        pa[10] += hv * q2.z;  pa[11] += hv * q2.w;
    }
#pragma unroll
    for (int j = 0; j < OUT_F; j++) {
        float vv = pa[j];
        vv += __shfl_xor(vv, 1, 64);  vv += __shfl_xor(vv, 2, 64);
        vv += __shfl_xor(vv, 4, 64);  vv += __shfl_xor(vv, 8, 64);
        vv += __shfl_xor(vv, 16, 64); vv += __shfl_xor(vv, 32, 64);
        pa[j] = vv;
    }
    if (lane == 0) {
#pragma unroll
        for (int j = 0; j < OUT_F; j++) red[w][j] = pa[j];
    }
    __syncthreads();
    if (t < OUT_F)
        atomicAdd(&out[g * OUT_F + t], red[0][t] + red[1][t] + red[2][t] + red[3][t]);
}

// ================================================================ launcher
extern "C" void kernel_launch(void* const* d_in, const int* in_sizes, int n_in,
                              void* d_out, int out_size, void* d_ws, size_t ws_size,
                              hipStream_t stream) {
    const float* x    = (const float*)d_in[0];
    const int*   edge = (const int*)d_in[1];
    const int*   src  = edge;
    const int*   dst  = edge + N_EDGES;
    const float* W1  = (const float*)d_in[3];
    const float* b1  = (const float*)d_in[4];
    const float* W2  = (const float*)d_in[5];
    const float* b2  = (const float*)d_in[6];
    const float* Wfc = (const float*)d_in[7];
    const float* bfc = (const float*)d_in[8];
    float* out = (float*)d_out;

    char* p = (char*)d_ws;
    auto alloc = [&](size_t n) { char* r = p; p += (n + 255) & ~(size_t)255; return r; };
    int*   gCursor    = (int*)alloc(256 * 4);
    int2*  rowinfo    = (int2*)alloc((size_t)N_NODES * 8);
    unsigned short* nbr = (unsigned short*)alloc((size_t)256 * CAP * 2 + 256); // pad: prefetch reads up to +63
    __half* g1h       = (__half*)alloc((size_t)N_NODES * F_IN * 2);
    __half* g2h       = (__half*)alloc((size_t)N_NODES * H * 2);
    float* a2         = (float*)alloc((size_t)N_NODES * H * 4);
    unsigned int* binned = (unsigned int*)alloc((size_t)256 * CAP * 4);

    init_kernel<<<1, 256, 0, stream>>>(gCursor, bfc, out);
    binA_kernel<<<256, 256, 0, stream>>>(src, dst, gCursor, binned);
    binB_g1_kernel<<<256, 256, 0, stream>>>(binned, gCursor, x, rowinfo, nbr,
                                            (__half2*)g1h);
    agg1_gemm1_kernel<<<N_NODES / NPB, 256, 0, stream>>>((const __half2*)g1h, rowinfo, nbr,
                                                         W1, b1, g2h);
    agg2_kernel<<<N_NODES / NPB, 256, 0, stream>>>((const __half2*)g2h, rowinfo, nbr, a2);
    gemm2_fc_kernel<<<N_NODES / 64, 256, 0, stream>>>(a2, W2, b2, Wfc, out);
}